// Round 7
// baseline (260.030 us; speedup 1.0000x reference)
//
#include <hip/hip_runtime.h>
#include <stdint.h>

// Problem constants: B=4, N=32768, K=16, nqueries=2048, stride=16.
#define NPTS  32768
#define NQ    2048
#define KNN   16
#define NB    4
#define BLOCK 256
#define WPB   4               // waves per block; 4 queries per wave

__device__ __forceinline__ int dpp_shr1_i(int x) {
    // row_shr:1 within 16-lane rows; row-start lane keeps old (bound_ctrl=0)
    return __builtin_amdgcn_update_dpp(x, x, 0x111, 0xf, 0xf, false);
}
__device__ __forceinline__ float dpp_shr1_f(float x) {
    return __int_as_float(dpp_shr1_i(__float_as_int(x)));
}
__device__ __forceinline__ float readlane_f(float x, int l) {
    return __int_as_float(__builtin_amdgcn_readlane(__float_as_int(x), l));
}

// Exact distributed top-16 for query t (0..3): sorted list (ascending by
// (dist,idx)) lives in lanes 16t..16t+15; lane 16t+15 is the exact threshold
// tau. d passed in is the EXACT numpy distance. tg = tau*(1+1e-5) is the
// conservative FMA-gate threshold, refreshed whenever tau changes.
__device__ __forceinline__ void insert_all(float d, int p, int lane, int t,
                                           float& ld, int& li, float& tau, float& tg)
{
    unsigned long long rem = __ballot(d <= tau);
    while (rem) {
        const int srcl = __ffsll(rem) - 1;           // wave-uniform
        const float wd = readlane_f(d, srcl);
        const int   wi = __builtin_amdgcn_readlane(p, srcl);
        const bool less = (ld < wd) || (ld == wd && li < wi);
        const unsigned long long lm = __ballot(less);
        const int pos = __popc((unsigned)((lm >> (16 * t)) & 0xffffull));
        const float pld = dpp_shr1_f(ld);
        const int   pli = dpp_shr1_i(li);
        if ((lane >> 4) == t) {
            const int gl = lane & 15;
            if (gl == pos)      { ld = wd;  li = wi;  }
            else if (gl > pos)  { ld = pld; li = pli; }
        }
        tau = readlane_f(ld, 16 * t + 15);
        tg  = tau * 1.00001f;                        // superset gate threshold
        rem &= rem - 1;
        if (rem) rem &= __ballot(d <= tau);          // re-gate survivors (exact)
    }
}

// No LDS, no barriers: 1.5 MB input is L2-resident on every XCD.
// 512 blocks x 4 waves = 2048 waves; 4 queries/wave; 2 waves/SIMD.
__global__ __launch_bounds__(BLOCK, 2) void knn_kernel(const float* __restrict__ xyz,
                                                       float* __restrict__ out_idx,
                                                       float* __restrict__ out_pts)
{
    const int tid  = threadIdx.x;
    const int lane = tid & 63;
    const int wv   = tid >> 6;
    const int w    = blockIdx.x * WPB + wv;          // wave id in [0, 2048)
    const int b    = w >> 9;                         // 512 waves per batch
    const int pr   = w & 511;                        // query-quad index
    const size_t base = (size_t)b * NPTS * 3;

    const int qp0 = pr << 6;                         // first query's point idx
    float qx[4], qy[4], qz[4];
    #pragma unroll
    for (int t = 0; t < 4; ++t) {
        qx[t] = xyz[base + 3 * (qp0 + 16 * t) + 0];
        qy[t] = xyz[base + 3 * (qp0 + 16 * t) + 1];
        qz[t] = xyz[base + 3 * (qp0 + 16 * t) + 2];
    }

    const int g0 = b * NQ + (pr << 2);               // first global query id
    if (lane < 12) {                                 // 12 floats of out_pts
        const int t = (lane * 11) >> 5;              // lane/3 for lane<12
        const int c = lane - 3 * t;
        out_pts[3 * g0 + lane] = xyz[base + 3 * (qp0 + 16 * t) + c];
    }

    float ld = __builtin_inff();  int li = 0x7fffffff;
    float tau[4] = { __builtin_inff(), __builtin_inff(),
                     __builtin_inff(), __builtin_inff() };
    float tg[4]  = { __builtin_inff(), __builtin_inff(),
                     __builtin_inff(), __builtin_inff() };

    // Lane's stream: points 4*lane..4*lane+3 of each 256-point chunk.
    const float4* lp = (const float4*)(xyz + base) + 3 * lane;

    #pragma unroll 2
    for (int k = 0; k < NPTS / 256; ++k) {
        const float4 A  = lp[192 * k + 0];           // (x0,y0,z0,x1)
        const float4 Bv = lp[192 * k + 1];           // (y1,z1,x2,y2)
        const float4 Cv = lp[192 * k + 2];           // (z2,x3,y3,z3)
        const float px[4] = { A.x,  A.w,  Bv.z, Cv.y };
        const float py[4] = { A.y,  Bv.x, Bv.w, Cv.z };
        const float pz[4] = { A.z,  Bv.y, Cv.x, Cv.w };

        // Fast gate: g = fma(dz,dz, fma(dy,dy, dx*dx)); |g-d| <= ~6ulp rel.
        unsigned long long ms[16];
        unsigned long long m = 0;
        #pragma unroll
        for (int t = 0; t < 4; ++t) {
            #pragma unroll
            for (int j = 0; j < 4; ++j) {
                const float dx = __fadd_rn(px[j], -qx[t]);
                const float dy = __fadd_rn(py[j], -qy[t]);
                const float dz = __fadd_rn(pz[j], -qz[t]);
                const float g  = __fmaf_rn(dz, dz, __fmaf_rn(dy, dy,
                                  __fmul_rn(dx, dx)));
                ms[4 * t + j] = __ballot(g <= tg[t]);
                m |= ms[4 * t + j];
            }
        }

        if (m) {
            const int pb = (k << 8) + 4 * lane;
            #pragma unroll
            for (int t = 0; t < 4; ++t) {
                #pragma unroll
                for (int j = 0; j < 4; ++j) {
                    if (ms[4 * t + j]) {
                        // exact numpy distance: ((dx*dx + dy*dy) + dz*dz)
                        const float dx = __fadd_rn(px[j], -qx[t]);
                        const float dy = __fadd_rn(py[j], -qy[t]);
                        const float dz = __fadd_rn(pz[j], -qz[t]);
                        const float d  = __fadd_rn(
                            __fadd_rn(__fmul_rn(dx, dx), __fmul_rn(dy, dy)),
                            __fmul_rn(dz, dz));
                        insert_all(d, pb + j, lane, t, ld, li, tau[t], tg[t]);
                    }
                }
            }
        }
    }

    // lanes 16t..16t+15: query g0+t ranks 0..15 -> one coalesced wave store
    out_idx[(size_t)g0 * KNN + lane] = (float)li;
}

extern "C" void kernel_launch(void* const* d_in, const int* in_sizes, int n_in,
                              void* d_out, int out_size, void* d_ws, size_t ws_size,
                              hipStream_t stream) {
    const float* xyz = (const float*)d_in[0];
    float* out = (float*)d_out;
    float* out_idx = out;                                 // NB*NQ*KNN floats
    float* out_pts = out + (size_t)NB * NQ * KNN;         // NB*NQ*3 floats

    const int blocks = (NB * NQ / 4) / WPB;               // 512
    knn_kernel<<<blocks, BLOCK, 0, stream>>>(xyz, out_idx, out_pts);
}

// Round 8
// 232.183 us; speedup vs baseline: 1.1199x; 1.1199x over previous
//
#include <hip/hip_runtime.h>
#include <stdint.h>

// Problem constants: B=4, N=32768, K=16, nqueries=2048, stride=16.
#define NPTS  32768
#define NQ    2048
#define KNN   16
#define NB    4
#define BLOCK 256
#define HALF  16384           // points per half-stream (split-K = 2)

__device__ __forceinline__ int dpp_shr1_i(int x) {
    // row_shr:1 within 16-lane rows; row-start lane keeps old (bound_ctrl=0)
    return __builtin_amdgcn_update_dpp(x, x, 0x111, 0xf, 0xf, false);
}
__device__ __forceinline__ float dpp_shr1_f(float x) {
    return __int_as_float(dpp_shr1_i(__float_as_int(x)));
}
__device__ __forceinline__ float readlane_f(float x, int l) {
    return __int_as_float(__builtin_amdgcn_readlane(__float_as_int(x), l));
}

// Exact distributed top-16 for query T (0/1): sorted list (ascending by
// (dist,idx)) in lanes 16T..16T+15; lane 16T+15 holds the exact threshold tau.
// d is the EXACT numpy distance. tg = tau*(1+1e-5) is the conservative
// FMA-gate threshold (margin 28x the fma-vs-numpy rounding gap), refreshed
// whenever tau changes.
template <int T>
__device__ __forceinline__ void insert_all(float d, int p, int lane,
                                           float& ld, int& li, float& tau, float& tg)
{
    unsigned long long rem = __ballot(d <= tau);
    while (rem) {
        const int srcl = __ffsll(rem) - 1;           // wave-uniform
        const float wd = readlane_f(d, srcl);
        const int   wi = __builtin_amdgcn_readlane(p, srcl);
        const bool less = (ld < wd) || (ld == wd && li < wi);
        const unsigned long long lm = __ballot(less);
        const int pos = __popc((unsigned)((lm >> (16 * T)) & 0xffffull));
        const float pld = dpp_shr1_f(ld);
        const int   pli = dpp_shr1_i(li);
        if ((lane >> 4) == T) {
            const int gl = lane & 15;
            if (gl == pos)      { ld = wd;  li = wi;  }
            else if (gl > pos)  { ld = pld; li = pli; }
        }
        tau = readlane_f(ld, 16 * T + 15);
        tg  = tau * 1.00001f;
        rem &= rem - 1;
        if (rem) rem &= __ballot(d <= tau);          // re-gate survivors (exact)
    }
}

// 2048 blocks x 4 waves = 8192 waves (32/CU, full residency).
// Wave = (query-pair, half): waves {2p, 2p+1} of a block stream disjoint
// point halves for the same 2 queries, then merge exactly via LDS.
__global__ __launch_bounds__(BLOCK, 6) void knn_kernel(const float* __restrict__ xyz,
                                                       float* __restrict__ out_idx,
                                                       float* __restrict__ out_pts)
{
    __shared__ float d_buf[2][2][2][KNN];            // [pair][query][half][rank]
    __shared__ int   i_buf[2][2][2][KNN];

    const int tid   = threadIdx.x;
    const int lane  = tid & 63;
    const int wv    = tid >> 6;
    const int pairw = wv >> 1;                       // pair within block (0/1)
    const int h     = wv & 1;                        // which point half
    const int qpg   = blockIdx.x * 2 + pairw;        // query-pair id [0, 4096)
    const int b     = qpg >> 10;                     // 1024 pairs per batch
    const int pr    = qpg & 1023;
    const size_t base = (size_t)b * NPTS * 3;

    const int qp0 = pr << 5;                         // stride-16 subsample
    const float qx0 = xyz[base + 3 * qp0 + 0];
    const float qy0 = xyz[base + 3 * qp0 + 1];
    const float qz0 = xyz[base + 3 * qp0 + 2];
    const float qx1 = xyz[base + 3 * qp0 + 48];
    const float qy1 = xyz[base + 3 * qp0 + 49];
    const float qz1 = xyz[base + 3 * qp0 + 50];

    const int g0 = b * NQ + (pr << 1);               // first global query id
    if (h == 0 && lane == 0) {
        out_pts[3 * g0 + 0] = qx0;
        out_pts[3 * g0 + 1] = qy0;
        out_pts[3 * g0 + 2] = qz0;
        out_pts[3 * g0 + 3] = qx1;
        out_pts[3 * g0 + 4] = qy1;
        out_pts[3 * g0 + 5] = qz1;
    }

    float ld = __builtin_inff();  int li = 0x7fffffff;
    float tau0 = __builtin_inff(), tau1 = __builtin_inff();
    float tg0  = __builtin_inff(), tg1  = __builtin_inff();

    // Lane's stream: points 4*lane..4*lane+3 of each 256-point chunk of its half.
    const float4* lp = (const float4*)(xyz + base) + h * (HALF * 3 / 4) + 3 * lane;

    #pragma unroll 2
    for (int k = 0; k < HALF / 256; ++k) {           // 64 iterations
        const float4 A  = lp[192 * k + 0];           // (x0,y0,z0,x1)
        const float4 Bv = lp[192 * k + 1];           // (y1,z1,x2,y2)
        const float4 Cv = lp[192 * k + 2];           // (z2,x3,y3,z3)
        const float px[4] = { A.x,  A.w,  Bv.z, Cv.y };
        const float py[4] = { A.y,  Bv.x, Bv.w, Cv.z };
        const float pz[4] = { A.z,  Bv.y, Cv.x, Cv.w };

        // Fast gate: g = fma(dz,dz, fma(dy,dy, dx*dx)); rel gap vs exact ~4ulp.
        unsigned long long m00, m01, m02, m03, m10, m11, m12, m13;
        {
            float dx, dy, dz, g;
            dx = px[0] - qx0; dy = py[0] - qy0; dz = pz[0] - qz0;
            g = __fmaf_rn(dz, dz, __fmaf_rn(dy, dy, __fmul_rn(dx, dx)));
            m00 = __ballot(g <= tg0);
            dx = px[1] - qx0; dy = py[1] - qy0; dz = pz[1] - qz0;
            g = __fmaf_rn(dz, dz, __fmaf_rn(dy, dy, __fmul_rn(dx, dx)));
            m01 = __ballot(g <= tg0);
            dx = px[2] - qx0; dy = py[2] - qy0; dz = pz[2] - qz0;
            g = __fmaf_rn(dz, dz, __fmaf_rn(dy, dy, __fmul_rn(dx, dx)));
            m02 = __ballot(g <= tg0);
            dx = px[3] - qx0; dy = py[3] - qy0; dz = pz[3] - qz0;
            g = __fmaf_rn(dz, dz, __fmaf_rn(dy, dy, __fmul_rn(dx, dx)));
            m03 = __ballot(g <= tg0);
            dx = px[0] - qx1; dy = py[0] - qy1; dz = pz[0] - qz1;
            g = __fmaf_rn(dz, dz, __fmaf_rn(dy, dy, __fmul_rn(dx, dx)));
            m10 = __ballot(g <= tg1);
            dx = px[1] - qx1; dy = py[1] - qy1; dz = pz[1] - qz1;
            g = __fmaf_rn(dz, dz, __fmaf_rn(dy, dy, __fmul_rn(dx, dx)));
            m11 = __ballot(g <= tg1);
            dx = px[2] - qx1; dy = py[2] - qy1; dz = pz[2] - qz1;
            g = __fmaf_rn(dz, dz, __fmaf_rn(dy, dy, __fmul_rn(dx, dx)));
            m12 = __ballot(g <= tg1);
            dx = px[3] - qx1; dy = py[3] - qy1; dz = pz[3] - qz1;
            g = __fmaf_rn(dz, dz, __fmaf_rn(dy, dy, __fmul_rn(dx, dx)));
            m13 = __ballot(g <= tg1);
        }

        if (m00 | m01 | m02 | m03 | m10 | m11 | m12 | m13) {
            const int pb = h * HALF + (k << 8) + 4 * lane;
            // exact numpy distance: ((dx*dx + dy*dy) + dz*dz), each op rn
            #define SLOW(mask, J, T, QX, QY, QZ, TAU, TGV)                          \
                if (mask) {                                                         \
                    const float dx = __fadd_rn(px[J], -(QX));                       \
                    const float dy = __fadd_rn(py[J], -(QY));                       \
                    const float dz = __fadd_rn(pz[J], -(QZ));                       \
                    const float d  = __fadd_rn(                                     \
                        __fadd_rn(__fmul_rn(dx, dx), __fmul_rn(dy, dy)),            \
                        __fmul_rn(dz, dz));                                         \
                    insert_all<T>(d, pb + J, lane, ld, li, TAU, TGV);               \
                }
            SLOW(m00, 0, 0, qx0, qy0, qz0, tau0, tg0)
            SLOW(m01, 1, 0, qx0, qy0, qz0, tau0, tg0)
            SLOW(m02, 2, 0, qx0, qy0, qz0, tau0, tg0)
            SLOW(m03, 3, 0, qx0, qy0, qz0, tau0, tg0)
            SLOW(m10, 0, 1, qx1, qy1, qz1, tau1, tg1)
            SLOW(m11, 1, 1, qx1, qy1, qz1, tau1, tg1)
            SLOW(m12, 2, 1, qx1, qy1, qz1, tau1, tg1)
            SLOW(m13, 3, 1, qx1, qy1, qz1, tau1, tg1)
            #undef SLOW
        }
    }

    // Publish this wave's two sorted 16-lists (exact distances + indices).
    if (lane < 32) {
        const int t = lane >> 4;
        d_buf[pairw][t][h][lane & 15] = ld;
        i_buf[pairw][t][h][lane & 15] = li;
    }
    __syncthreads();

    // Wave h==0 of each pair merges the two halves exactly: rank by strict
    // (d, idx) order over the 32 candidates (disjoint point sets -> total
    // order; matches top_k's stable lowest-index-first tie-break).
    if (h == 0) {
        const int t = lane >> 5;                     // query within pair
        const int s = lane & 31;                     // candidate slot
        const float d = d_buf[pairw][t][s >> 4][s & 15];
        const int   i = i_buf[pairw][t][s >> 4][s & 15];
        int cnt = 0;
        #pragma unroll
        for (int r = 0; r < 32; ++r) {
            const float od = d_buf[pairw][t][r >> 4][r & 15];
            const int   oi = i_buf[pairw][t][r >> 4][r & 15];
            cnt += ((od < d) || (od == d && oi < i)) ? 1 : 0;
        }
        if (cnt < KNN)
            out_idx[(size_t)(g0 + t) * KNN + cnt] = (float)i;
    }
}

extern "C" void kernel_launch(void* const* d_in, const int* in_sizes, int n_in,
                              void* d_out, int out_size, void* d_ws, size_t ws_size,
                              hipStream_t stream) {
    const float* xyz = (const float*)d_in[0];
    float* out = (float*)d_out;
    float* out_idx = out;                                 // NB*NQ*KNN floats
    float* out_pts = out + (size_t)NB * NQ * KNN;         // NB*NQ*3 floats

    const int blocks = (NB * NQ / 2) / 2;                 // 2048 (2 pairs/block)
    knn_kernel<<<blocks, BLOCK, 0, stream>>>(xyz, out_idx, out_pts);
}

// Round 9
// 195.723 us; speedup vs baseline: 1.3286x; 1.1863x over previous
//
#include <hip/hip_runtime.h>
#include <stdint.h>

// Problem constants: B=4, N=32768, K=16, nqueries=2048, stride=16.
#define NPTS  32768
#define NQ    2048
#define KNN   16
#define NB    4
#define BLOCK 256
#define WPB   4               // waves per block; 2 queries per wave
#define PPL   8               // points per lane per iteration (16 ILP chains)
#define ITERS (NPTS / (64 * PPL))   // 64

__device__ __forceinline__ int dpp_shr1_i(int x) {
    // row_shr:1 within 16-lane rows; row-start lane keeps old (bound_ctrl=0)
    return __builtin_amdgcn_update_dpp(x, x, 0x111, 0xf, 0xf, false);
}
__device__ __forceinline__ float dpp_shr1_f(float x) {
    return __int_as_float(dpp_shr1_i(__float_as_int(x)));
}
__device__ __forceinline__ float readlane_f(float x, int l) {
    return __int_as_float(__builtin_amdgcn_readlane(__float_as_int(x), l));
}

// Exact distributed top-16 for query T (0/1): sorted list (ascending by
// (dist,idx)) in lanes 16T..16T+15; lane 16T+15 holds the exact threshold tau.
// d is the EXACT numpy distance. tg = tau*(1+1e-5) is the conservative
// FMA-gate threshold (margin ~40x the fma-vs-numpy rounding gap).
template <int T>
__device__ __forceinline__ void insert_all(float d, int p, int lane,
                                           float& ld, int& li, float& tau, float& tg)
{
    unsigned long long rem = __ballot(d <= tau);
    while (rem) {
        const int srcl = __ffsll(rem) - 1;           // wave-uniform
        const float wd = readlane_f(d, srcl);
        const int   wi = __builtin_amdgcn_readlane(p, srcl);
        const bool less = (ld < wd) || (ld == wd && li < wi);
        const unsigned long long lm = __ballot(less);
        const int pos = __popc((unsigned)((lm >> (16 * T)) & 0xffffull));
        const float pld = dpp_shr1_f(ld);
        const int   pli = dpp_shr1_i(li);
        if ((lane >> 4) == T) {
            const int gl = lane & 15;
            if (gl == pos)      { ld = wd;  li = wi;  }
            else if (gl > pos)  { ld = pld; li = pli; }
        }
        tau = readlane_f(ld, 16 * T + 15);
        tg  = tau * 1.00001f;
        rem &= rem - 1;
        if (rem) rem &= __ballot(d <= tau);          // re-gate survivors (exact)
    }
}

__device__ __forceinline__ void load6(float4 dst[6], const float4* p) {
    #pragma unroll
    for (int t = 0; t < 6; ++t) dst[t] = p[t];
}

// One 512-point step: 8 pts/lane, 16 independent FMA-gate chains, exact
// recompute + exact insert for accepted slots.
__device__ __forceinline__ void step(const float4 c[6], int pb, int lane,
                                     float qx0, float qy0, float qz0,
                                     float qx1, float qy1, float qz1,
                                     float& ld, int& li,
                                     float& tau0, float& tau1,
                                     float& tg0, float& tg1)
{
    float px[PPL], py[PPL], pz[PPL];                 // pure register renames
    px[0] = c[0].x; py[0] = c[0].y; pz[0] = c[0].z;
    px[1] = c[0].w; py[1] = c[1].x; pz[1] = c[1].y;
    px[2] = c[1].z; py[2] = c[1].w; pz[2] = c[2].x;
    px[3] = c[2].y; py[3] = c[2].z; pz[3] = c[2].w;
    px[4] = c[3].x; py[4] = c[3].y; pz[4] = c[3].z;
    px[5] = c[3].w; py[5] = c[4].x; pz[5] = c[4].y;
    px[6] = c[4].z; py[6] = c[4].w; pz[6] = c[5].x;
    px[7] = c[5].y; py[7] = c[5].z; pz[7] = c[5].w;

    unsigned long long m0[PPL], m1[PPL], any = 0;
    #pragma unroll
    for (int j = 0; j < PPL; ++j) {                  // 16 independent chains
        const float ax = px[j] - qx0, ay = py[j] - qy0, az = pz[j] - qz0;
        const float g0 = __fmaf_rn(az, az, __fmaf_rn(ay, ay, __fmul_rn(ax, ax)));
        m0[j] = __ballot(g0 <= tg0);
        const float bx = px[j] - qx1, by = py[j] - qy1, bz = pz[j] - qz1;
        const float g1 = __fmaf_rn(bz, bz, __fmaf_rn(by, by, __fmul_rn(bx, bx)));
        m1[j] = __ballot(g1 <= tg1);
        any |= m0[j] | m1[j];
    }
    if (any) {
        #pragma unroll
        for (int j = 0; j < PPL; ++j) {
            if (m0[j]) {                             // exact numpy distance
                const float dx = __fadd_rn(px[j], -qx0);
                const float dy = __fadd_rn(py[j], -qy0);
                const float dz = __fadd_rn(pz[j], -qz0);
                const float d  = __fadd_rn(
                    __fadd_rn(__fmul_rn(dx, dx), __fmul_rn(dy, dy)),
                    __fmul_rn(dz, dz));
                insert_all<0>(d, pb + j, lane, ld, li, tau0, tg0);
            }
        }
        #pragma unroll
        for (int j = 0; j < PPL; ++j) {
            if (m1[j]) {
                const float dx = __fadd_rn(px[j], -qx1);
                const float dy = __fadd_rn(py[j], -qy1);
                const float dz = __fadd_rn(pz[j], -qz1);
                const float d  = __fadd_rn(
                    __fadd_rn(__fmul_rn(dx, dx), __fmul_rn(dy, dy)),
                    __fmul_rn(dz, dz));
                insert_all<1>(d, pb + j, lane, ld, li, tau1, tg1);
            }
        }
    }
}

// No LDS, no barriers: 1.5 MB input is L2-resident. 1024 blocks x 4 waves =
// 4096 waves (16/CU, 4/SIMD at VGPR<=128); ILP-first register budget.
__global__ __launch_bounds__(BLOCK, 4) void knn_kernel(const float* __restrict__ xyz,
                                                       float* __restrict__ out_idx,
                                                       float* __restrict__ out_pts)
{
    const int tid  = threadIdx.x;
    const int lane = tid & 63;
    const int wv   = tid >> 6;
    const int w    = blockIdx.x * WPB + wv;          // wave id in [0, 4096)
    const int b    = w >> 10;
    const int pr   = w & 1023;                       // query pair
    const size_t base = (size_t)b * NPTS * 3;

    const int qp0 = pr << 5;                         // stride-16 subsample
    const float qx0 = xyz[base + 3 * qp0 + 0];
    const float qy0 = xyz[base + 3 * qp0 + 1];
    const float qz0 = xyz[base + 3 * qp0 + 2];
    const float qx1 = xyz[base + 3 * qp0 + 48];
    const float qy1 = xyz[base + 3 * qp0 + 49];
    const float qz1 = xyz[base + 3 * qp0 + 50];

    const int g0 = b * NQ + (pr << 1);
    if (lane == 0) {
        out_pts[3 * g0 + 0] = qx0;
        out_pts[3 * g0 + 1] = qy0;
        out_pts[3 * g0 + 2] = qz0;
        out_pts[3 * g0 + 3] = qx1;
        out_pts[3 * g0 + 4] = qy1;
        out_pts[3 * g0 + 5] = qz1;
    }

    float ld = __builtin_inff();  int li = 0x7fffffff;
    float tau0 = __builtin_inff(), tau1 = __builtin_inff();
    float tg0  = __builtin_inff(), tg1  = __builtin_inff();

    // Lane's stream: 8 consecutive points (6 float4) per iteration.
    const float4* lp = (const float4*)(xyz + base) + 6 * lane;

    float4 A[6], Bf[6];
    load6(A, lp);                                    // prologue
    for (int k = 0; k < ITERS; k += 2) {             // double-buffered pipeline
        load6(Bf, lp + 384);                         // prefetch iter k+1
        step(A, (k << 9) + PPL * lane, lane,
             qx0, qy0, qz0, qx1, qy1, qz1, ld, li, tau0, tau1, tg0, tg1);
        if (k + 2 < ITERS)
            load6(A, lp + 768);                      // prefetch iter k+2
        step(Bf, ((k + 1) << 9) + PPL * lane, lane,
             qx0, qy0, qz0, qx1, qy1, qz1, ld, li, tau0, tau1, tg0, tg1);
        lp += 768;
    }

    // lanes 0..15: q0 ranks 0..15; lanes 16..31: q1 ranks (g1 = g0+1)
    if (lane < 2 * KNN) {
        out_idx[(size_t)g0 * KNN + lane] = (float)li;
    }
}

extern "C" void kernel_launch(void* const* d_in, const int* in_sizes, int n_in,
                              void* d_out, int out_size, void* d_ws, size_t ws_size,
                              hipStream_t stream) {
    const float* xyz = (const float*)d_in[0];
    float* out = (float*)d_out;
    float* out_idx = out;                                 // NB*NQ*KNN floats
    float* out_pts = out + (size_t)NB * NQ * KNN;         // NB*NQ*3 floats

    const int blocks = (NB * NQ / 2) / WPB;               // 1024
    knn_kernel<<<blocks, BLOCK, 0, stream>>>(xyz, out_idx, out_pts);
}